// Round 3
// baseline (3534.367 us; speedup 1.0000x reference)
//
#include <hip/hip_runtime.h>
#include <math.h>

#define BB 8
#define NN 325
#define TT 24
#define DD 64
#define HH 8
#define MM 16
#define E2 128
#define DK 16
#define NEG 0.1f

#define GG 4
#define NB ((NN + GG - 1) / GG)   // 82 node-groups per batch
#define PADE 132

// arena layout (bytes): overlay of proj-input vs per-g attention buffers
//   phase A: s_in[GG][TT][E2]                    = 49152 B
//   phase B: s_q[TT][PADE] s_k[..] s_v[..] s_val[TT][E2] = 38016 + 12288 = 50304 B
#define ARENA_BYTES 50304
#define OFF_Q 0
#define OFF_K 12672
#define OFF_V 25344
#define OFF_VAL 38016

// ---------------- K1: tfeat[b][m] = tanh(mean_t(tXin[b,0,t,:]) @ tproj_w + tproj_b)
__global__ void k_tfeat(const float* __restrict__ tXin, const float* __restrict__ tproj_w,
                        const float* __restrict__ tproj_b, float* __restrict__ tfeat) {
    int b = blockIdx.x;
    int d = threadIdx.x;  // 64 threads
    __shared__ float mv[DD];
    float a = 0.f;
    for (int t = 0; t < TT; ++t)
        a += tXin[((size_t)(b * NN + 0) * TT + t) * DD + d];
    mv[d] = a * (1.f / (float)TT);
    __syncthreads();
    if (d < MM) {
        float acc = tproj_b[d];
        for (int j = 0; j < DD; ++j) acc += mv[j] * tproj_w[j * MM + d];
        tfeat[b * MM + d] = tanhf(acc);
    }
}

// ---------------- K2: support = einsum('btnm,bmtd->bntd'); gcn_out = relu(support@gcn_w + b)
#define TN 64
__global__ __launch_bounds__(256) void k_gcn(const float* __restrict__ matrix,
                                             const float* __restrict__ hidden,
                                             const float* __restrict__ gcn_w,
                                             const float* __restrict__ gcn_b,
                                             float* __restrict__ gcn_out) {
    int bt = blockIdx.x;
    int tile = blockIdx.y;
    int b = bt / TT, t = bt % TT;
    int n0 = tile * TN;

    __shared__ float s_mat[TN][68];
    __shared__ float s_H[64][DD];
    __shared__ float s_gw[DD][DD];

    int tid = threadIdx.x;
    for (int idx = tid; idx < DD * DD; idx += 256)
        s_gw[idx / DD][idx % DD] = gcn_w[idx];

    int r  = tid >> 3;
    int d0 = (tid & 7) << 3;
    float acc0[8], acc1[8];
#pragma unroll
    for (int i = 0; i < 8; ++i) { acc0[i] = 0.f; acc1[i] = 0.f; }

    for (int m0 = 0; m0 < NN; m0 += 64) {
        __syncthreads();
        for (int idx = tid; idx < TN * 64; idx += 256) {
            int rr = idx >> 6, cc = idx & 63;
            int n = n0 + rr, m = m0 + cc;
            s_mat[rr][cc] = (n < NN && m < NN) ? matrix[((size_t)(b * TT + t) * NN + n) * NN + m] : 0.f;
        }
        for (int idx = tid; idx < 64 * DD; idx += 256) {
            int mm = idx >> 6, d = idx & 63;
            int m = m0 + mm;
            s_H[mm][d] = (m < NN) ? hidden[((size_t)(b * NN + m) * TT + t) * DD + d] : 0.f;
        }
        __syncthreads();
        int mmax = (NN - m0 < 64) ? (NN - m0) : 64;
        for (int mm = 0; mm < mmax; ++mm) {
            float w0 = s_mat[r][mm];
            float w1 = s_mat[r + 32][mm];
            float4 h0 = *(const float4*)&s_H[mm][d0];
            float4 h1 = *(const float4*)&s_H[mm][d0 + 4];
            acc0[0] += w0 * h0.x; acc0[1] += w0 * h0.y; acc0[2] += w0 * h0.z; acc0[3] += w0 * h0.w;
            acc0[4] += w0 * h1.x; acc0[5] += w0 * h1.y; acc0[6] += w0 * h1.z; acc0[7] += w0 * h1.w;
            acc1[0] += w1 * h0.x; acc1[1] += w1 * h0.y; acc1[2] += w1 * h0.z; acc1[3] += w1 * h0.w;
            acc1[4] += w1 * h1.x; acc1[5] += w1 * h1.y; acc1[6] += w1 * h1.z; acc1[7] += w1 * h1.w;
        }
    }

    __syncthreads();
    *(float4*)&s_H[r][d0]          = make_float4(acc0[0], acc0[1], acc0[2], acc0[3]);
    *(float4*)&s_H[r][d0 + 4]      = make_float4(acc0[4], acc0[5], acc0[6], acc0[7]);
    *(float4*)&s_H[r + 32][d0]     = make_float4(acc1[0], acc1[1], acc1[2], acc1[3]);
    *(float4*)&s_H[r + 32][d0 + 4] = make_float4(acc1[4], acc1[5], acc1[6], acc1[7]);
    __syncthreads();

    float g0[8], g1[8];
#pragma unroll
    for (int i = 0; i < 8; ++i) { g0[i] = gcn_b[d0 + i]; g1[i] = g0[i]; }
    for (int d = 0; d < DD; ++d) {
        float s0 = s_H[r][d], s1 = s_H[r + 32][d];
        float4 w0 = *(const float4*)&s_gw[d][d0];
        float4 w1 = *(const float4*)&s_gw[d][d0 + 4];
        g0[0] += s0 * w0.x; g0[1] += s0 * w0.y; g0[2] += s0 * w0.z; g0[3] += s0 * w0.w;
        g0[4] += s0 * w1.x; g0[5] += s0 * w1.y; g0[6] += s0 * w1.z; g0[7] += s0 * w1.w;
        g1[0] += s1 * w0.x; g1[1] += s1 * w0.y; g1[2] += s1 * w0.z; g1[3] += s1 * w0.w;
        g1[4] += s1 * w1.x; g1[5] += s1 * w1.y; g1[6] += s1 * w1.z; g1[7] += s1 * w1.w;
    }
#pragma unroll
    for (int i = 0; i < 8; ++i) {
        g0[i] = g0[i] > 0.f ? g0[i] : 0.f;
        g1[i] = g1[i] > 0.f ? g1[i] : 0.f;
    }
    if (n0 + r < NN) {
        size_t base = ((size_t)(b * NN + (n0 + r)) * TT + t) * DD;
        *(float4*)&gcn_out[base + d0]     = make_float4(g0[0], g0[1], g0[2], g0[3]);
        *(float4*)&gcn_out[base + d0 + 4] = make_float4(g0[4], g0[5], g0[6], g0[7]);
    }
    if (n0 + r + 32 < NN) {
        size_t base = ((size_t)(b * NN + (n0 + r + 32)) * TT + t) * DD;
        *(float4*)&gcn_out[base + d0]     = make_float4(g1[0], g1[1], g1[2], g1[3]);
        *(float4*)&gcn_out[base + d0 + 4] = make_float4(g1[4], g1[5], g1[6], g1[7]);
    }
}

// ---------------- K3: fused per-(b, 4 nodes)
__global__ __launch_bounds__(384, 3) void k_attn(
    const float* __restrict__ hidden, const float* __restrict__ tXin,
    const float* __restrict__ node_emb, const float* __restrict__ tfeat,
    const float* __restrict__ WQ, const float* __restrict__ WK, const float* __restrict__ WV,
    const float* __restrict__ out_w, const float* __restrict__ out_b,
    const float* __restrict__ gate_w, const float* __restrict__ gate_b,
    const float* __restrict__ gcn_out, float* __restrict__ out) {
    int bn = blockIdx.x;
    int b = bn / NB, n0 = (bn % NB) * GG;
    int tid = threadIdx.x;

    __shared__ __align__(16) char arena[ARENA_BYTES];
    __shared__ __align__(16) float s_e[MM][GG];     // [m][g]
    __shared__ float s_gcn[TT][DD];
    __shared__ float s_value[TT][DD];

    float* s_in = (float*)arena;                    // [GG][TT][E2]

    // ---- phase 0: emb coeffs + inputs
    if (tid < MM * GG) {
        int m = tid >> 2, g = tid & 3;
        int n = n0 + g;
        s_e[m][g] = (n < NN) ? node_emb[n * MM + m] * tfeat[b * MM + m] : 0.f;
    }
    for (int idx = tid; idx < GG * TT * (E2 / 4); idx += 384) {
        int g = idx / (TT * 32);
        int r = idx % (TT * 32);
        int t = r >> 5, i4 = r & 31;
        int n = n0 + g;
        float4 v = make_float4(0.f, 0.f, 0.f, 0.f);
        if (n < NN) {
            size_t base = ((size_t)(b * NN + n) * TT + t) * DD;
            v = (i4 < 16) ? *(const float4*)&hidden[base + i4 * 4]
                          : *(const float4*)&tXin[base + (i4 - 16) * 4];
        }
        *(float4*)&s_in[((g * TT + t) * E2) + i4 * 4] = v;
    }
    __syncthreads();

    // ---- proj: thread (p,k) computes column k of projection p for all 4 nodes, all t
    int p = tid >> 7;          // 0=Q 1=K 2=V (wave-uniform: 2 waves per p)
    int k = tid & 127;
    const float* __restrict__ W = (p == 0) ? WQ : ((p == 1) ? WK : WV);
    const float* __restrict__ Wk = W + k;

    float acc[GG][TT];
#pragma unroll
    for (int g = 0; g < GG; ++g)
#pragma unroll
        for (int t = 0; t < TT; ++t) acc[g][t] = 0.f;

    for (int i0 = 0; i0 < E2; i0 += 4) {
        float wp[GG][4];
#pragma unroll
        for (int g = 0; g < GG; ++g)
#pragma unroll
            for (int ii = 0; ii < 4; ++ii) wp[g][ii] = 0.f;

        const float* wb = Wk + (size_t)i0 * E2;
#pragma unroll
        for (int m = 0; m < MM; ++m) {
            const float4 ev = *(const float4*)&s_e[m][0];   // broadcast
            const float* wm = wb + (size_t)m * (E2 * E2);
            float w0 = wm[0];
            float w1 = wm[E2];
            float w2 = wm[2 * E2];
            float w3 = wm[3 * E2];
            wp[0][0] += ev.x * w0; wp[0][1] += ev.x * w1; wp[0][2] += ev.x * w2; wp[0][3] += ev.x * w3;
            wp[1][0] += ev.y * w0; wp[1][1] += ev.y * w1; wp[1][2] += ev.y * w2; wp[1][3] += ev.y * w3;
            wp[2][0] += ev.z * w0; wp[2][1] += ev.z * w1; wp[2][2] += ev.z * w2; wp[2][3] += ev.z * w3;
            wp[3][0] += ev.w * w0; wp[3][1] += ev.w * w1; wp[3][2] += ev.w * w2; wp[3][3] += ev.w * w3;
        }
#pragma unroll
        for (int t = 0; t < TT; ++t) {
#pragma unroll
            for (int g = 0; g < GG; ++g) {
                const float4 x = *(const float4*)&s_in[(g * TT + t) * E2 + i0];
                acc[g][t] += x.x * wp[g][0] + x.y * wp[g][1] + x.z * wp[g][2] + x.w * wp[g][3];
            }
        }
    }
    __syncthreads();   // s_in dead; arena becomes q/k/v/val

    float* s_q   = (float*)(arena + OFF_Q);    // [TT][PADE]
    float* s_k   = (float*)(arena + OFF_K);
    float* s_v   = (float*)(arena + OFF_V);
    float* s_val = (float*)(arena + OFF_VAL);  // [TT][E2]

    int tq = tid >> 4;          // 0..23  (t for out-proj/gate)
    int dd0 = (tid & 15) * 4;   // dd quad

#pragma unroll
    for (int g = 0; g < GG; ++g) {
        bool valid = (n0 + g < NN);
        if (valid) {
            float* dst = (p == 0) ? s_q : ((p == 1) ? s_k : s_v);
#pragma unroll
            for (int t = 0; t < TT; ++t) {
                float a = acc[g][t];
                dst[t * PADE + k] = (a >= 0.f) ? a : NEG * a;
            }
        }
        __syncthreads();

        if (valid) {
            if (tid < HH * TT) {
                int h = tid / TT, t = tid % TT;
                const float scale = 0.25f;
                float4 q0 = *(const float4*)&s_q[t * PADE + h * DK];
                float4 q1 = *(const float4*)&s_q[t * PADE + h * DK + 4];
                float4 q2 = *(const float4*)&s_q[t * PADE + h * DK + 8];
                float4 q3 = *(const float4*)&s_q[t * PADE + h * DK + 12];
                float sum = 0.f;
                float val[DK];
#pragma unroll
                for (int d = 0; d < DK; ++d) val[d] = 0.f;
                for (int s = 0; s <= t; ++s) {
                    float4 k0 = *(const float4*)&s_k[s * PADE + h * DK];
                    float4 k1 = *(const float4*)&s_k[s * PADE + h * DK + 4];
                    float4 k2 = *(const float4*)&s_k[s * PADE + h * DK + 8];
                    float4 k3 = *(const float4*)&s_k[s * PADE + h * DK + 12];
                    float dot = q0.x * k0.x + q0.y * k0.y + q0.z * k0.z + q0.w * k0.w
                              + q1.x * k1.x + q1.y * k1.y + q1.z * k1.z + q1.w * k1.w
                              + q2.x * k2.x + q2.y * k2.y + q2.z * k2.z + q2.w * k2.w
                              + q3.x * k3.x + q3.y * k3.y + q3.z * k3.z + q3.w * k3.w;
                    float w = __expf(dot * scale);
                    sum += w;
                    float4 v0 = *(const float4*)&s_v[s * PADE + h * DK];
                    float4 v1 = *(const float4*)&s_v[s * PADE + h * DK + 4];
                    float4 v2 = *(const float4*)&s_v[s * PADE + h * DK + 8];
                    float4 v3 = *(const float4*)&s_v[s * PADE + h * DK + 12];
                    val[0] += w * v0.x;  val[1] += w * v0.y;  val[2] += w * v0.z;  val[3] += w * v0.w;
                    val[4] += w * v1.x;  val[5] += w * v1.y;  val[6] += w * v1.z;  val[7] += w * v1.w;
                    val[8] += w * v2.x;  val[9] += w * v2.y;  val[10] += w * v2.z; val[11] += w * v2.w;
                    val[12] += w * v3.x; val[13] += w * v3.y; val[14] += w * v3.z; val[15] += w * v3.w;
                }
                float inv = 1.f / sum;
#pragma unroll
                for (int d = 0; d < DK; ++d) s_val[t * E2 + h * DK + d] = val[d] * inv;
            } else {
                size_t base = (size_t)(b * NN + n0 + g) * TT * DD;
                for (int idx = tid - 192; idx < TT * DD; idx += 192)
                    s_gcn[idx >> 6][idx & 63] = gcn_out[base + idx];
            }
        }
        __syncthreads();

        if (valid) {
            // value[t][dd0:4] = lrelu(out_b + val[t,:] @ out_w[:,dd0:4])
            float4 a = *(const float4*)&out_b[dd0];
            for (int j0 = 0; j0 < E2; j0 += 4) {
                const float4 x = *(const float4*)&s_val[tq * E2 + j0];
                const float4 w0 = *(const float4*)&out_w[(j0 + 0) * DD + dd0];
                const float4 w1 = *(const float4*)&out_w[(j0 + 1) * DD + dd0];
                const float4 w2 = *(const float4*)&out_w[(j0 + 2) * DD + dd0];
                const float4 w3 = *(const float4*)&out_w[(j0 + 3) * DD + dd0];
                a.x += x.x * w0.x + x.y * w1.x + x.z * w2.x + x.w * w3.x;
                a.y += x.x * w0.y + x.y * w1.y + x.z * w2.y + x.w * w3.y;
                a.z += x.x * w0.z + x.y * w1.z + x.z * w2.z + x.w * w3.z;
                a.w += x.x * w0.w + x.y * w1.w + x.z * w2.w + x.w * w3.w;
            }
            a.x = (a.x >= 0.f) ? a.x : NEG * a.x;
            a.y = (a.y >= 0.f) ? a.y : NEG * a.y;
            a.z = (a.z >= 0.f) ? a.z : NEG * a.z;
            a.w = (a.w >= 0.f) ? a.w : NEG * a.w;
            *(float4*)&s_value[tq][dd0] = a;
        }
        __syncthreads();

        if (valid) {
            float4 zz = *(const float4*)&gate_b[dd0];
            for (int j0 = 0; j0 < DD; j0 += 4) {
                const float4 x = *(const float4*)&s_gcn[tq][j0];
                const float4 w0 = *(const float4*)&gate_w[(j0 + 0) * DD + dd0];
                const float4 w1 = *(const float4*)&gate_w[(j0 + 1) * DD + dd0];
                const float4 w2 = *(const float4*)&gate_w[(j0 + 2) * DD + dd0];
                const float4 w3 = *(const float4*)&gate_w[(j0 + 3) * DD + dd0];
                zz.x += x.x * w0.x + x.y * w1.x + x.z * w2.x + x.w * w3.x;
                zz.y += x.x * w0.y + x.y * w1.y + x.z * w2.y + x.w * w3.y;
                zz.z += x.x * w0.z + x.y * w1.z + x.z * w2.z + x.w * w3.z;
                zz.w += x.x * w0.w + x.y * w1.w + x.z * w2.w + x.w * w3.w;
            }
            for (int j0 = 0; j0 < DD; j0 += 4) {
                const float4 x = *(const float4*)&s_value[tq][j0];
                const float4 w0 = *(const float4*)&gate_w[(DD + j0 + 0) * DD + dd0];
                const float4 w1 = *(const float4*)&gate_w[(DD + j0 + 1) * DD + dd0];
                const float4 w2 = *(const float4*)&gate_w[(DD + j0 + 2) * DD + dd0];
                const float4 w3 = *(const float4*)&gate_w[(DD + j0 + 3) * DD + dd0];
                zz.x += x.x * w0.x + x.y * w1.x + x.z * w2.x + x.w * w3.x;
                zz.y += x.x * w0.y + x.y * w1.y + x.z * w2.y + x.w * w3.y;
                zz.z += x.x * w0.z + x.y * w1.z + x.z * w2.z + x.w * w3.z;
                zz.w += x.x * w0.w + x.y * w1.w + x.z * w2.w + x.w * w3.w;
            }
            size_t base = (size_t)(b * NN + n0 + g) * TT * DD + tq * DD + dd0;
            const float4 hv = *(const float4*)&hidden[base];
            const float4 gv = *(const float4*)&s_gcn[tq][dd0];
            const float4 vv = *(const float4*)&s_value[tq][dd0];
            float4 o;
            float z;
            z = 1.f / (1.f + __expf(-zz.x)); o.x = z * gv.x + (1.f - z) * vv.x + hv.x;
            z = 1.f / (1.f + __expf(-zz.y)); o.y = z * gv.y + (1.f - z) * vv.y + hv.y;
            z = 1.f / (1.f + __expf(-zz.z)); o.z = z * gv.z + (1.f - z) * vv.z + hv.z;
            z = 1.f / (1.f + __expf(-zz.w)); o.w = z * gv.w + (1.f - z) * vv.w + hv.w;
            *(float4*)&out[base] = o;
        }
        __syncthreads();
    }
}

extern "C" void kernel_launch(void* const* d_in, const int* in_sizes, int n_in,
                              void* d_out, int out_size, void* d_ws, size_t ws_size,
                              hipStream_t stream) {
    const float* hidden   = (const float*)d_in[0];
    const float* tXin     = (const float*)d_in[1];
    const float* matrix   = (const float*)d_in[2];
    const float* gcn_w    = (const float*)d_in[3];
    const float* gcn_b    = (const float*)d_in[4];
    const float* node_emb = (const float*)d_in[5];
    const float* tproj_w  = (const float*)d_in[6];
    const float* tproj_b  = (const float*)d_in[7];
    const float* WK_      = (const float*)d_in[8];   // dict order: WK, WQ, WV
    const float* WQ_      = (const float*)d_in[9];
    const float* WV_      = (const float*)d_in[10];
    const float* out_w    = (const float*)d_in[11];
    const float* out_b    = (const float*)d_in[12];
    const float* gate_w   = (const float*)d_in[13];
    const float* gate_b   = (const float*)d_in[14];
    float* out = (float*)d_out;

    float* tfeat   = (float*)d_ws;          // 128 floats
    float* gcn_out = tfeat + 128;           // B*N*T*D floats (~16 MB)

    k_tfeat<<<BB, DD, 0, stream>>>(tXin, tproj_w, tproj_b, tfeat);
    k_gcn<<<dim3(BB * TT, (NN + TN - 1) / TN), 256, 0, stream>>>(matrix, hidden, gcn_w, gcn_b, gcn_out);
    k_attn<<<BB * NB, 384, 0, stream>>>(hidden, tXin, node_emb, tfeat, WQ_, WK_, WV_,
                                        out_w, out_b, gate_w, gate_b, gcn_out, out);
}

// Round 4
// 2177.322 us; speedup vs baseline: 1.6233x; 1.6233x over previous
//
#include <hip/hip_runtime.h>
#include <math.h>

#define BB 8
#define NN 325
#define TT 24
#define DD 64
#define HH 8
#define MM 16
#define E2 128
#define DK 16
#define NEG 0.1f

#define GG 4
#define NB ((NN + GG - 1) / GG)   // 82 node-groups per batch
#define PADE 132

// arena layout (bytes): overlay of proj-input vs per-g attention buffers
//   phase A: s_in[GG][TT][E2]                    = 49152 B
//   phase B: s_q[TT][PADE] s_k[..] s_v[..] s_val[TT][E2] = 38016 + 12288 = 50304 B
#define ARENA_BYTES 50304
#define OFF_Q 0
#define OFF_K 12672
#define OFF_V 25344
#define OFF_VAL 38016

// ---------------- K1: tfeat[b][m] = tanh(mean_t(tXin[b,0,t,:]) @ tproj_w + tproj_b)
__global__ void k_tfeat(const float* __restrict__ tXin, const float* __restrict__ tproj_w,
                        const float* __restrict__ tproj_b, float* __restrict__ tfeat) {
    int b = blockIdx.x;
    int d = threadIdx.x;  // 64 threads
    __shared__ float mv[DD];
    float a = 0.f;
    for (int t = 0; t < TT; ++t)
        a += tXin[((size_t)(b * NN + 0) * TT + t) * DD + d];
    mv[d] = a * (1.f / (float)TT);
    __syncthreads();
    if (d < MM) {
        float acc = tproj_b[d];
        for (int j = 0; j < DD; ++j) acc += mv[j] * tproj_w[j * MM + d];
        tfeat[b * MM + d] = tanhf(acc);
    }
}

// ---------------- K2: support = einsum('btnm,bmtd->bntd'); gcn_out = relu(support@gcn_w + b)
#define TN 64
__global__ __launch_bounds__(256) void k_gcn(const float* __restrict__ matrix,
                                             const float* __restrict__ hidden,
                                             const float* __restrict__ gcn_w,
                                             const float* __restrict__ gcn_b,
                                             float* __restrict__ gcn_out) {
    int bt = blockIdx.x;
    int tile = blockIdx.y;
    int b = bt / TT, t = bt % TT;
    int n0 = tile * TN;

    __shared__ float s_mat[TN][68];
    __shared__ float s_H[64][DD];
    __shared__ float s_gw[DD][DD];

    int tid = threadIdx.x;
    for (int idx = tid; idx < DD * DD; idx += 256)
        s_gw[idx / DD][idx % DD] = gcn_w[idx];

    int r  = tid >> 3;
    int d0 = (tid & 7) << 3;
    float acc0[8], acc1[8];
#pragma unroll
    for (int i = 0; i < 8; ++i) { acc0[i] = 0.f; acc1[i] = 0.f; }

    for (int m0 = 0; m0 < NN; m0 += 64) {
        __syncthreads();
        for (int idx = tid; idx < TN * 64; idx += 256) {
            int rr = idx >> 6, cc = idx & 63;
            int n = n0 + rr, m = m0 + cc;
            s_mat[rr][cc] = (n < NN && m < NN) ? matrix[((size_t)(b * TT + t) * NN + n) * NN + m] : 0.f;
        }
        for (int idx = tid; idx < 64 * DD; idx += 256) {
            int mm = idx >> 6, d = idx & 63;
            int m = m0 + mm;
            s_H[mm][d] = (m < NN) ? hidden[((size_t)(b * NN + m) * TT + t) * DD + d] : 0.f;
        }
        __syncthreads();
        int mmax = (NN - m0 < 64) ? (NN - m0) : 64;
        for (int mm = 0; mm < mmax; ++mm) {
            float w0 = s_mat[r][mm];
            float w1 = s_mat[r + 32][mm];
            float4 h0 = *(const float4*)&s_H[mm][d0];
            float4 h1 = *(const float4*)&s_H[mm][d0 + 4];
            acc0[0] += w0 * h0.x; acc0[1] += w0 * h0.y; acc0[2] += w0 * h0.z; acc0[3] += w0 * h0.w;
            acc0[4] += w0 * h1.x; acc0[5] += w0 * h1.y; acc0[6] += w0 * h1.z; acc0[7] += w0 * h1.w;
            acc1[0] += w1 * h0.x; acc1[1] += w1 * h0.y; acc1[2] += w1 * h0.z; acc1[3] += w1 * h0.w;
            acc1[4] += w1 * h1.x; acc1[5] += w1 * h1.y; acc1[6] += w1 * h1.z; acc1[7] += w1 * h1.w;
        }
    }

    __syncthreads();
    *(float4*)&s_H[r][d0]          = make_float4(acc0[0], acc0[1], acc0[2], acc0[3]);
    *(float4*)&s_H[r][d0 + 4]      = make_float4(acc0[4], acc0[5], acc0[6], acc0[7]);
    *(float4*)&s_H[r + 32][d0]     = make_float4(acc1[0], acc1[1], acc1[2], acc1[3]);
    *(float4*)&s_H[r + 32][d0 + 4] = make_float4(acc1[4], acc1[5], acc1[6], acc1[7]);
    __syncthreads();

    float g0[8], g1[8];
#pragma unroll
    for (int i = 0; i < 8; ++i) { g0[i] = gcn_b[d0 + i]; g1[i] = g0[i]; }
    for (int d = 0; d < DD; ++d) {
        float s0 = s_H[r][d], s1 = s_H[r + 32][d];
        float4 w0 = *(const float4*)&s_gw[d][d0];
        float4 w1 = *(const float4*)&s_gw[d][d0 + 4];
        g0[0] += s0 * w0.x; g0[1] += s0 * w0.y; g0[2] += s0 * w0.z; g0[3] += s0 * w0.w;
        g0[4] += s0 * w1.x; g0[5] += s0 * w1.y; g0[6] += s0 * w1.z; g0[7] += s0 * w1.w;
        g1[0] += s1 * w0.x; g1[1] += s1 * w0.y; g1[2] += s1 * w0.z; g1[3] += s1 * w0.w;
        g1[4] += s1 * w1.x; g1[5] += s1 * w1.y; g1[6] += s1 * w1.z; g1[7] += s1 * w1.w;
    }
#pragma unroll
    for (int i = 0; i < 8; ++i) {
        g0[i] = g0[i] > 0.f ? g0[i] : 0.f;
        g1[i] = g1[i] > 0.f ? g1[i] : 0.f;
    }
    if (n0 + r < NN) {
        size_t base = ((size_t)(b * NN + (n0 + r)) * TT + t) * DD;
        *(float4*)&gcn_out[base + d0]     = make_float4(g0[0], g0[1], g0[2], g0[3]);
        *(float4*)&gcn_out[base + d0 + 4] = make_float4(g0[4], g0[5], g0[6], g0[7]);
    }
    if (n0 + r + 32 < NN) {
        size_t base = ((size_t)(b * NN + (n0 + r + 32)) * TT + t) * DD;
        *(float4*)&gcn_out[base + d0]     = make_float4(g1[0], g1[1], g1[2], g1[3]);
        *(float4*)&gcn_out[base + d0 + 4] = make_float4(g1[4], g1[5], g1[6], g1[7]);
    }
}

// ---------------- K3: fused per-(b, 4 nodes)
// waves_per_eu(2,3): min 2 (VGPR cap 256, no 84-reg spill disaster), max 3 (allocator
// targets ~170 regs -> acc[4][24] stays in registers; 2 blocks/CU via 63KB LDS)
__global__ __launch_bounds__(384)
__attribute__((amdgpu_waves_per_eu(2, 3)))
void k_attn(
    const float* __restrict__ hidden, const float* __restrict__ tXin,
    const float* __restrict__ node_emb, const float* __restrict__ tfeat,
    const float* __restrict__ WQ, const float* __restrict__ WK, const float* __restrict__ WV,
    const float* __restrict__ out_w, const float* __restrict__ out_b,
    const float* __restrict__ gate_w, const float* __restrict__ gate_b,
    const float* __restrict__ gcn_out, float* __restrict__ out) {
    int bn = blockIdx.x;
    int b = bn / NB, n0 = (bn % NB) * GG;
    int tid = threadIdx.x;

    __shared__ __align__(16) char arena[ARENA_BYTES];
    __shared__ __align__(16) float s_e[MM][GG];     // [m][g]
    __shared__ float s_gcn[TT][DD];
    __shared__ float s_value[TT][DD];

    float* s_in = (float*)arena;                    // [GG][TT][E2]

    // ---- phase 0: emb coeffs + inputs
    if (tid < MM * GG) {
        int m = tid >> 2, g = tid & 3;
        int n = n0 + g;
        s_e[m][g] = (n < NN) ? node_emb[n * MM + m] * tfeat[b * MM + m] : 0.f;
    }
    for (int idx = tid; idx < GG * TT * (E2 / 4); idx += 384) {
        int g = idx / (TT * 32);
        int r = idx % (TT * 32);
        int t = r >> 5, i4 = r & 31;
        int n = n0 + g;
        float4 v = make_float4(0.f, 0.f, 0.f, 0.f);
        if (n < NN) {
            size_t base = ((size_t)(b * NN + n) * TT + t) * DD;
            v = (i4 < 16) ? *(const float4*)&hidden[base + i4 * 4]
                          : *(const float4*)&tXin[base + (i4 - 16) * 4];
        }
        *(float4*)&s_in[((g * TT + t) * E2) + i4 * 4] = v;
    }
    __syncthreads();

    // ---- proj: thread (p,k) computes column k of projection p for all 4 nodes, all t
    int p = tid >> 7;          // 0=Q 1=K 2=V (wave-uniform: 2 waves per p)
    int k = tid & 127;
    const float* __restrict__ W = (p == 0) ? WQ : ((p == 1) ? WK : WV);
    const float* __restrict__ Wk = W + k;

    float acc[GG][TT];
#pragma unroll
    for (int g = 0; g < GG; ++g)
#pragma unroll
        for (int t = 0; t < TT; ++t) acc[g][t] = 0.f;

    for (int i0 = 0; i0 < E2; i0 += 4) {
        float wp[GG][4];
#pragma unroll
        for (int g = 0; g < GG; ++g)
#pragma unroll
            for (int ii = 0; ii < 4; ++ii) wp[g][ii] = 0.f;

        const float* wb = Wk + (size_t)i0 * E2;
        // two half-batches of m: load 32 independent coalesced scalars into regs,
        // THEN run the dependent wp-FMA chain (gives the scheduler a prefetch window)
#pragma unroll
        for (int mg = 0; mg < 2; ++mg) {
            float w[8][4];
#pragma unroll
            for (int mm = 0; mm < 8; ++mm) {
                const float* wm = wb + (size_t)(mg * 8 + mm) * (E2 * E2);
                w[mm][0] = wm[0];
                w[mm][1] = wm[E2];
                w[mm][2] = wm[2 * E2];
                w[mm][3] = wm[3 * E2];
            }
#pragma unroll
            for (int mm = 0; mm < 8; ++mm) {
                const float4 ev = *(const float4*)&s_e[mg * 8 + mm][0];   // broadcast
                wp[0][0] += ev.x * w[mm][0]; wp[0][1] += ev.x * w[mm][1]; wp[0][2] += ev.x * w[mm][2]; wp[0][3] += ev.x * w[mm][3];
                wp[1][0] += ev.y * w[mm][0]; wp[1][1] += ev.y * w[mm][1]; wp[1][2] += ev.y * w[mm][2]; wp[1][3] += ev.y * w[mm][3];
                wp[2][0] += ev.z * w[mm][0]; wp[2][1] += ev.z * w[mm][1]; wp[2][2] += ev.z * w[mm][2]; wp[2][3] += ev.z * w[mm][3];
                wp[3][0] += ev.w * w[mm][0]; wp[3][1] += ev.w * w[mm][1]; wp[3][2] += ev.w * w[mm][2]; wp[3][3] += ev.w * w[mm][3];
            }
        }
#pragma unroll
        for (int t = 0; t < TT; ++t) {
#pragma unroll
            for (int g = 0; g < GG; ++g) {
                const float4 x = *(const float4*)&s_in[(g * TT + t) * E2 + i0];
                acc[g][t] += x.x * wp[g][0] + x.y * wp[g][1] + x.z * wp[g][2] + x.w * wp[g][3];
            }
        }
    }
    __syncthreads();   // s_in dead; arena becomes q/k/v/val

    float* s_q   = (float*)(arena + OFF_Q);    // [TT][PADE]
    float* s_k   = (float*)(arena + OFF_K);
    float* s_v   = (float*)(arena + OFF_V);
    float* s_val = (float*)(arena + OFF_VAL);  // [TT][E2]

    int tq = tid >> 4;          // 0..23  (t for out-proj/gate)
    int dd0 = (tid & 15) * 4;   // dd quad

#pragma unroll
    for (int g = 0; g < GG; ++g) {
        bool valid = (n0 + g < NN);
        if (valid) {
            float* dst = (p == 0) ? s_q : ((p == 1) ? s_k : s_v);
#pragma unroll
            for (int t = 0; t < TT; ++t) {
                float a = acc[g][t];
                dst[t * PADE + k] = (a >= 0.f) ? a : NEG * a;
            }
        }
        __syncthreads();

        if (valid) {
            if (tid < HH * TT) {
                int h = tid / TT, t = tid % TT;
                const float scale = 0.25f;
                float4 q0 = *(const float4*)&s_q[t * PADE + h * DK];
                float4 q1 = *(const float4*)&s_q[t * PADE + h * DK + 4];
                float4 q2 = *(const float4*)&s_q[t * PADE + h * DK + 8];
                float4 q3 = *(const float4*)&s_q[t * PADE + h * DK + 12];
                float sum = 0.f;
                float val[DK];
#pragma unroll
                for (int d = 0; d < DK; ++d) val[d] = 0.f;
                for (int s = 0; s <= t; ++s) {
                    float4 k0 = *(const float4*)&s_k[s * PADE + h * DK];
                    float4 k1 = *(const float4*)&s_k[s * PADE + h * DK + 4];
                    float4 k2 = *(const float4*)&s_k[s * PADE + h * DK + 8];
                    float4 k3 = *(const float4*)&s_k[s * PADE + h * DK + 12];
                    float dot = q0.x * k0.x + q0.y * k0.y + q0.z * k0.z + q0.w * k0.w
                              + q1.x * k1.x + q1.y * k1.y + q1.z * k1.z + q1.w * k1.w
                              + q2.x * k2.x + q2.y * k2.y + q2.z * k2.z + q2.w * k2.w
                              + q3.x * k3.x + q3.y * k3.y + q3.z * k3.z + q3.w * k3.w;
                    float w = __expf(dot * scale);
                    sum += w;
                    float4 v0 = *(const float4*)&s_v[s * PADE + h * DK];
                    float4 v1 = *(const float4*)&s_v[s * PADE + h * DK + 4];
                    float4 v2 = *(const float4*)&s_v[s * PADE + h * DK + 8];
                    float4 v3 = *(const float4*)&s_v[s * PADE + h * DK + 12];
                    val[0] += w * v0.x;  val[1] += w * v0.y;  val[2] += w * v0.z;  val[3] += w * v0.w;
                    val[4] += w * v1.x;  val[5] += w * v1.y;  val[6] += w * v1.z;  val[7] += w * v1.w;
                    val[8] += w * v2.x;  val[9] += w * v2.y;  val[10] += w * v2.z; val[11] += w * v2.w;
                    val[12] += w * v3.x; val[13] += w * v3.y; val[14] += w * v3.z; val[15] += w * v3.w;
                }
                float inv = 1.f / sum;
#pragma unroll
                for (int d = 0; d < DK; ++d) s_val[t * E2 + h * DK + d] = val[d] * inv;
            } else {
                size_t base = (size_t)(b * NN + n0 + g) * TT * DD;
                for (int idx = tid - 192; idx < TT * DD; idx += 192)
                    s_gcn[idx >> 6][idx & 63] = gcn_out[base + idx];
            }
        }
        __syncthreads();

        if (valid) {
            // value[t][dd0:4] = lrelu(out_b + val[t,:] @ out_w[:,dd0:4])
            float4 a = *(const float4*)&out_b[dd0];
            for (int j0 = 0; j0 < E2; j0 += 4) {
                const float4 x = *(const float4*)&s_val[tq * E2 + j0];
                const float4 w0 = *(const float4*)&out_w[(j0 + 0) * DD + dd0];
                const float4 w1 = *(const float4*)&out_w[(j0 + 1) * DD + dd0];
                const float4 w2 = *(const float4*)&out_w[(j0 + 2) * DD + dd0];
                const float4 w3 = *(const float4*)&out_w[(j0 + 3) * DD + dd0];
                a.x += x.x * w0.x + x.y * w1.x + x.z * w2.x + x.w * w3.x;
                a.y += x.x * w0.y + x.y * w1.y + x.z * w2.y + x.w * w3.y;
                a.z += x.x * w0.z + x.y * w1.z + x.z * w2.z + x.w * w3.z;
                a.w += x.x * w0.w + x.y * w1.w + x.z * w2.w + x.w * w3.w;
            }
            a.x = (a.x >= 0.f) ? a.x : NEG * a.x;
            a.y = (a.y >= 0.f) ? a.y : NEG * a.y;
            a.z = (a.z >= 0.f) ? a.z : NEG * a.z;
            a.w = (a.w >= 0.f) ? a.w : NEG * a.w;
            *(float4*)&s_value[tq][dd0] = a;
        }
        __syncthreads();

        if (valid) {
            float4 zz = *(const float4*)&gate_b[dd0];
            for (int j0 = 0; j0 < DD; j0 += 4) {
                const float4 x = *(const float4*)&s_gcn[tq][j0];
                const float4 w0 = *(const float4*)&gate_w[(j0 + 0) * DD + dd0];
                const float4 w1 = *(const float4*)&gate_w[(j0 + 1) * DD + dd0];
                const float4 w2 = *(const float4*)&gate_w[(j0 + 2) * DD + dd0];
                const float4 w3 = *(const float4*)&gate_w[(j0 + 3) * DD + dd0];
                zz.x += x.x * w0.x + x.y * w1.x + x.z * w2.x + x.w * w3.x;
                zz.y += x.x * w0.y + x.y * w1.y + x.z * w2.y + x.w * w3.y;
                zz.z += x.x * w0.z + x.y * w1.z + x.z * w2.z + x.w * w3.z;
                zz.w += x.x * w0.w + x.y * w1.w + x.z * w2.w + x.w * w3.w;
            }
            for (int j0 = 0; j0 < DD; j0 += 4) {
                const float4 x = *(const float4*)&s_value[tq][j0];
                const float4 w0 = *(const float4*)&gate_w[(DD + j0 + 0) * DD + dd0];
                const float4 w1 = *(const float4*)&gate_w[(DD + j0 + 1) * DD + dd0];
                const float4 w2 = *(const float4*)&gate_w[(DD + j0 + 2) * DD + dd0];
                const float4 w3 = *(const float4*)&gate_w[(DD + j0 + 3) * DD + dd0];
                zz.x += x.x * w0.x + x.y * w1.x + x.z * w2.x + x.w * w3.x;
                zz.y += x.x * w0.y + x.y * w1.y + x.z * w2.y + x.w * w3.y;
                zz.z += x.x * w0.z + x.y * w1.z + x.z * w2.z + x.w * w3.z;
                zz.w += x.x * w0.w + x.y * w1.w + x.z * w2.w + x.w * w3.w;
            }
            size_t base = (size_t)(b * NN + n0 + g) * TT * DD + tq * DD + dd0;
            const float4 hv = *(const float4*)&hidden[base];
            const float4 gv = *(const float4*)&s_gcn[tq][dd0];
            const float4 vv = *(const float4*)&s_value[tq][dd0];
            float4 o;
            float z;
            z = 1.f / (1.f + __expf(-zz.x)); o.x = z * gv.x + (1.f - z) * vv.x + hv.x;
            z = 1.f / (1.f + __expf(-zz.y)); o.y = z * gv.y + (1.f - z) * vv.y + hv.y;
            z = 1.f / (1.f + __expf(-zz.z)); o.z = z * gv.z + (1.f - z) * vv.z + hv.z;
            z = 1.f / (1.f + __expf(-zz.w)); o.w = z * gv.w + (1.f - z) * vv.w + hv.w;
            *(float4*)&out[base] = o;
        }
        __syncthreads();
    }
}

extern "C" void kernel_launch(void* const* d_in, const int* in_sizes, int n_in,
                              void* d_out, int out_size, void* d_ws, size_t ws_size,
                              hipStream_t stream) {
    const float* hidden   = (const float*)d_in[0];
    const float* tXin     = (const float*)d_in[1];
    const float* matrix   = (const float*)d_in[2];
    const float* gcn_w    = (const float*)d_in[3];
    const float* gcn_b    = (const float*)d_in[4];
    const float* node_emb = (const float*)d_in[5];
    const float* tproj_w  = (const float*)d_in[6];
    const float* tproj_b  = (const float*)d_in[7];
    const float* WK_      = (const float*)d_in[8];   // dict order: WK, WQ, WV
    const float* WQ_      = (const float*)d_in[9];
    const float* WV_      = (const float*)d_in[10];
    const float* out_w    = (const float*)d_in[11];
    const float* out_b    = (const float*)d_in[12];
    const float* gate_w   = (const float*)d_in[13];
    const float* gate_b   = (const float*)d_in[14];
    float* out = (float*)d_out;

    float* tfeat   = (float*)d_ws;          // 128 floats
    float* gcn_out = tfeat + 128;           // B*N*T*D floats (~16 MB)

    k_tfeat<<<BB, DD, 0, stream>>>(tXin, tproj_w, tproj_b, tfeat);
    k_gcn<<<dim3(BB * TT, (NN + TN - 1) / TN), 256, 0, stream>>>(matrix, hidden, gcn_w, gcn_b, gcn_out);
    k_attn<<<BB * NB, 384, 0, stream>>>(hidden, tXin, node_emb, tfeat, WQ_, WK_, WV_,
                                        out_w, out_b, gate_w, gate_b, gcn_out, out);
}

// Round 5
// 623.199 us; speedup vs baseline: 5.6713x; 3.4938x over previous
//
#include <hip/hip_runtime.h>
#include <math.h>

#define BB 8
#define NN 325
#define TT 24
#define DD 64
#define HH 8
#define MM 16
#define E2 128
#define DK 16
#define NEG 0.1f
#define NNODE (BB * NN)          // 2600
#define PADE 132

__device__ __forceinline__ unsigned short f2bf(float f) {
    union { float f; unsigned u; } v; v.f = f;
    unsigned r = v.u + 0x7fffu + ((v.u >> 16) & 1u);   // RNE
    return (unsigned short)(r >> 16);
}

// ---------------- K1: tfeat[b][m] = tanh(mean_t(tXin[b,0,t,:]) @ tproj_w + tproj_b)
__global__ void k_tfeat(const float* __restrict__ tXin, const float* __restrict__ tproj_w,
                        const float* __restrict__ tproj_b, float* __restrict__ tfeat) {
    int b = blockIdx.x;
    int d = threadIdx.x;  // 64 threads
    __shared__ float mv[DD];
    float a = 0.f;
    for (int t = 0; t < TT; ++t)
        a += tXin[((size_t)(b * NN + 0) * TT + t) * DD + d];
    mv[d] = a * (1.f / (float)TT);
    __syncthreads();
    if (d < MM) {
        float acc = tproj_b[d];
        for (int j = 0; j < DD; ++j) acc += mv[j] * tproj_w[j * MM + d];
        tfeat[b * MM + d] = tanhf(acc);
    }
}

// ---------------- K2: support = einsum('btnm,bmtd->bntd'); gcn_out = relu(support@gcn_w + b)
#define TN 64
__global__ __launch_bounds__(256) void k_gcn(const float* __restrict__ matrix,
                                             const float* __restrict__ hidden,
                                             const float* __restrict__ gcn_w,
                                             const float* __restrict__ gcn_b,
                                             float* __restrict__ gcn_out) {
    int bt = blockIdx.x;
    int tile = blockIdx.y;
    int b = bt / TT, t = bt % TT;
    int n0 = tile * TN;

    __shared__ float s_mat[TN][68];
    __shared__ float s_H[64][DD];
    __shared__ float s_gw[DD][DD];

    int tid = threadIdx.x;
    for (int idx = tid; idx < DD * DD; idx += 256)
        s_gw[idx / DD][idx % DD] = gcn_w[idx];

    int r  = tid >> 3;
    int d0 = (tid & 7) << 3;
    float acc0[8], acc1[8];
#pragma unroll
    for (int i = 0; i < 8; ++i) { acc0[i] = 0.f; acc1[i] = 0.f; }

    for (int m0 = 0; m0 < NN; m0 += 64) {
        __syncthreads();
        for (int idx = tid; idx < TN * 64; idx += 256) {
            int rr = idx >> 6, cc = idx & 63;
            int n = n0 + rr, m = m0 + cc;
            s_mat[rr][cc] = (n < NN && m < NN) ? matrix[((size_t)(b * TT + t) * NN + n) * NN + m] : 0.f;
        }
        for (int idx = tid; idx < 64 * DD; idx += 256) {
            int mm = idx >> 6, d = idx & 63;
            int m = m0 + mm;
            s_H[mm][d] = (m < NN) ? hidden[((size_t)(b * NN + m) * TT + t) * DD + d] : 0.f;
        }
        __syncthreads();
        int mmax = (NN - m0 < 64) ? (NN - m0) : 64;
        for (int mm = 0; mm < mmax; ++mm) {
            float w0 = s_mat[r][mm];
            float w1 = s_mat[r + 32][mm];
            float4 h0 = *(const float4*)&s_H[mm][d0];
            float4 h1 = *(const float4*)&s_H[mm][d0 + 4];
            acc0[0] += w0 * h0.x; acc0[1] += w0 * h0.y; acc0[2] += w0 * h0.z; acc0[3] += w0 * h0.w;
            acc0[4] += w0 * h1.x; acc0[5] += w0 * h1.y; acc0[6] += w0 * h1.z; acc0[7] += w0 * h1.w;
            acc1[0] += w1 * h0.x; acc1[1] += w1 * h0.y; acc1[2] += w1 * h0.z; acc1[3] += w1 * h0.w;
            acc1[4] += w1 * h1.x; acc1[5] += w1 * h1.y; acc1[6] += w1 * h1.z; acc1[7] += w1 * h1.w;
        }
    }

    __syncthreads();
    *(float4*)&s_H[r][d0]          = make_float4(acc0[0], acc0[1], acc0[2], acc0[3]);
    *(float4*)&s_H[r][d0 + 4]      = make_float4(acc0[4], acc0[5], acc0[6], acc0[7]);
    *(float4*)&s_H[r + 32][d0]     = make_float4(acc1[0], acc1[1], acc1[2], acc1[3]);
    *(float4*)&s_H[r + 32][d0 + 4] = make_float4(acc1[4], acc1[5], acc1[6], acc1[7]);
    __syncthreads();

    float g0[8], g1[8];
#pragma unroll
    for (int i = 0; i < 8; ++i) { g0[i] = gcn_b[d0 + i]; g1[i] = g0[i]; }
    for (int d = 0; d < DD; ++d) {
        float s0 = s_H[r][d], s1 = s_H[r + 32][d];
        float4 w0 = *(const float4*)&s_gw[d][d0];
        float4 w1 = *(const float4*)&s_gw[d][d0 + 4];
        g0[0] += s0 * w0.x; g0[1] += s0 * w0.y; g0[2] += s0 * w0.z; g0[3] += s0 * w0.w;
        g0[4] += s0 * w1.x; g0[5] += s0 * w1.y; g0[6] += s0 * w1.z; g0[7] += s0 * w1.w;
        g1[0] += s1 * w0.x; g1[1] += s1 * w0.y; g1[2] += s1 * w0.z; g1[3] += s1 * w0.w;
        g1[4] += s1 * w1.x; g1[5] += s1 * w1.y; g1[6] += s1 * w1.z; g1[7] += s1 * w1.w;
    }
#pragma unroll
    for (int i = 0; i < 8; ++i) {
        g0[i] = g0[i] > 0.f ? g0[i] : 0.f;
        g1[i] = g1[i] > 0.f ? g1[i] : 0.f;
    }
    if (n0 + r < NN) {
        size_t base = ((size_t)(b * NN + (n0 + r)) * TT + t) * DD;
        *(float4*)&gcn_out[base + d0]     = make_float4(g0[0], g0[1], g0[2], g0[3]);
        *(float4*)&gcn_out[base + d0 + 4] = make_float4(g0[4], g0[5], g0[6], g0[7]);
    }
    if (n0 + r + 32 < NN) {
        size_t base = ((size_t)(b * NN + (n0 + r + 32)) * TT + t) * DD;
        *(float4*)&gcn_out[base + d0]     = make_float4(g1[0], g1[1], g1[2], g1[3]);
        *(float4*)&gcn_out[base + d0 + 4] = make_float4(g1[4], g1[5], g1[6], g1[7]);
    }
}

// ---------------- K3a: Wp[u][p][i][k] (bf16) = sum_m e[u][m] * W_p[m][i][k]
// grid (ceil(Uc/8), 48); block 256. 8 nodes share each W read; W stays L2-resident.
__global__ __launch_bounds__(256) void k_wp(
    const float* __restrict__ node_emb, const float* __restrict__ tfeat,
    const float* __restrict__ WQ, const float* __restrict__ WK, const float* __restrict__ WV,
    unsigned short* __restrict__ wp, int u0, int Uc) {
    int un0 = blockIdx.x * 8;
    int chunk = blockIdx.y;                 // 0..47
    int p = chunk >> 4;                     // 0=Q 1=K 2=V
    int off = (chunk & 15) << 10;           // 1024-col chunk within 16384
    int tid = threadIdx.x;
    const float* __restrict__ W = (p == 0) ? WQ : ((p == 1) ? WK : WV);

    __shared__ float s_e[8][MM];
    if (tid < 8 * MM) {
        int nn = tid >> 4, m = tid & 15;
        int us = un0 + nn;
        float e = 0.f;
        if (us < Uc) {
            int u = u0 + us;
            int b = u / NN, n = u % NN;
            e = node_emb[n * MM + m] * tfeat[b * MM + m];
        }
        s_e[nn][m] = e;
    }
    __syncthreads();

    int j = off + tid * 4;
    float4 acc[8];
#pragma unroll
    for (int nn = 0; nn < 8; ++nn) acc[nn] = make_float4(0.f, 0.f, 0.f, 0.f);
#pragma unroll
    for (int m = 0; m < MM; ++m) {
        float4 w = *(const float4*)&W[(size_t)m * 16384 + j];
#pragma unroll
        for (int nn = 0; nn < 8; ++nn) {
            float e = s_e[nn][m];
            acc[nn].x += e * w.x; acc[nn].y += e * w.y;
            acc[nn].z += e * w.z; acc[nn].w += e * w.w;
        }
    }
#pragma unroll
    for (int nn = 0; nn < 8; ++nn) {
        int us = un0 + nn;
        if (us < Uc) {
            uint2 pk;
            pk.x = (unsigned)f2bf(acc[nn].x) | ((unsigned)f2bf(acc[nn].y) << 16);
            pk.y = (unsigned)f2bf(acc[nn].z) | ((unsigned)f2bf(acc[nn].w) << 16);
            *(uint2*)&wp[(size_t)us * 49152 + (size_t)p * 16384 + j] = pk;
        }
    }
}

// ---------------- K3b: per node: qkv_bf16 = lrelu(x @ Wp), streaming Wp once via LDS
// block 256 = 4 t-groups(6 t) x 64 k-pairs; acc[3][6][2]=36 regs. LDS 36 KB -> 4 blocks/CU.
__global__ __launch_bounds__(256) void k_proj(
    const float* __restrict__ hidden, const float* __restrict__ tXin,
    const unsigned short* __restrict__ wp, unsigned* __restrict__ qkv,
    int u0, int Uc) {
    int us = blockIdx.x;
    int u = u0 + us;
    int tid = threadIdx.x;

    __shared__ float s_x[TT][E2];          // 12 KB
    __shared__ unsigned s_w[3][32][64];    // 24 KB (bf16 pairs)

    size_t base = (size_t)u * TT * DD;
    for (int idx = tid; idx < TT * 32; idx += 256) {
        int t = idx >> 5, q4 = idx & 31;
        float4 v = (q4 < 16) ? *(const float4*)&hidden[base + t * DD + q4 * 4]
                             : *(const float4*)&tXin[base + t * DD + (q4 - 16) * 4];
        *(float4*)&s_x[t][q4 * 4] = v;
    }

    int kg = tid & 63, tg = tid >> 6;
    int t0 = tg * 6;
    float acc[3][6][2];
#pragma unroll
    for (int p = 0; p < 3; ++p)
#pragma unroll
        for (int tt = 0; tt < 6; ++tt) { acc[p][tt][0] = 0.f; acc[p][tt][1] = 0.f; }

    const size_t wpb = (size_t)us * 49152;
    for (int ic = 0; ic < 4; ++ic) {
        __syncthreads();
#pragma unroll
        for (int p = 0; p < 3; ++p) {
            const uint4* src = (const uint4*)(wp + wpb + p * 16384 + ic * 4096);
            uint4* dst = (uint4*)&s_w[p][0][0];
            dst[tid] = src[tid];
            dst[tid + 256] = src[tid + 256];
        }
        __syncthreads();
#pragma unroll 4
        for (int i = 0; i < 32; ++i) {
            float xv[6];
#pragma unroll
            for (int tt = 0; tt < 6; ++tt) xv[tt] = s_x[t0 + tt][ic * 32 + i];
#pragma unroll
            for (int p = 0; p < 3; ++p) {
                unsigned w = s_w[p][i][kg];
                float lo = __uint_as_float(w << 16);
                float hi = __uint_as_float(w & 0xffff0000u);
#pragma unroll
                for (int tt = 0; tt < 6; ++tt) {
                    acc[p][tt][0] += xv[tt] * lo;
                    acc[p][tt][1] += xv[tt] * hi;
                }
            }
        }
    }

    // lrelu + pack bf16 pairs: qkv[((us*3+p)*TT+t)*64 + kg]
#pragma unroll
    for (int p = 0; p < 3; ++p)
#pragma unroll
        for (int tt = 0; tt < 6; ++tt) {
            float a0 = acc[p][tt][0]; a0 = (a0 >= 0.f) ? a0 : NEG * a0;
            float a1 = acc[p][tt][1]; a1 = (a1 >= 0.f) ? a1 : NEG * a1;
            unsigned pk = (unsigned)f2bf(a0) | ((unsigned)f2bf(a1) << 16);
            qkv[((size_t)(us * 3 + p) * TT + (t0 + tt)) * 64 + kg] = pk;
        }
}

// ---------------- K3c: per node: attention + out-proj + gate + residual
__global__ __launch_bounds__(384) void k_attn2(
    const unsigned* __restrict__ qkv, const float* __restrict__ hidden,
    const float* __restrict__ out_w, const float* __restrict__ out_b,
    const float* __restrict__ gate_w, const float* __restrict__ gate_b,
    const float* __restrict__ gcn_out, float* __restrict__ out,
    int u0, int Uc) {
    int us = blockIdx.x;
    int u = u0 + us;
    int tid = threadIdx.x;

    __shared__ float s_q[TT][PADE];        // 12.7 KB each
    __shared__ float s_k[TT][PADE];
    __shared__ float s_v[TT][PADE];
    __shared__ float s_val[TT][E2];        // 12 KB
    __shared__ float s_gcn[TT][DD];        // 6 KB
    __shared__ float s_value[TT][DD];      // 6 KB

    // unpack bf16 qkv -> fp32 LDS
    for (int idx = tid; idx < 3 * TT * 64; idx += 384) {
        int p = idx / (TT * 64);
        int r = idx % (TT * 64);
        int t = r >> 6, kg = r & 63;
        unsigned w = qkv[(size_t)idx + (size_t)us * 3 * TT * 64];
        float lo = __uint_as_float(w << 16);
        float hi = __uint_as_float(w & 0xffff0000u);
        float* dst = (p == 0) ? &s_q[0][0] : ((p == 1) ? &s_k[0][0] : &s_v[0][0]);
        *(float2*)&dst[t * PADE + kg * 2] = make_float2(lo, hi);
    }
    size_t base = (size_t)u * TT * DD;
    __syncthreads();

    if (tid < HH * TT) {
        int h = tid / TT, t = tid % TT;
        const float scale = 0.25f;
        float4 q0 = *(const float4*)&s_q[t][h * DK];
        float4 q1 = *(const float4*)&s_q[t][h * DK + 4];
        float4 q2 = *(const float4*)&s_q[t][h * DK + 8];
        float4 q3 = *(const float4*)&s_q[t][h * DK + 12];
        float sum = 0.f;
        float val[DK];
#pragma unroll
        for (int d = 0; d < DK; ++d) val[d] = 0.f;
        for (int s = 0; s <= t; ++s) {
            float4 k0 = *(const float4*)&s_k[s][h * DK];
            float4 k1 = *(const float4*)&s_k[s][h * DK + 4];
            float4 k2 = *(const float4*)&s_k[s][h * DK + 8];
            float4 k3 = *(const float4*)&s_k[s][h * DK + 12];
            float dot = q0.x * k0.x + q0.y * k0.y + q0.z * k0.z + q0.w * k0.w
                      + q1.x * k1.x + q1.y * k1.y + q1.z * k1.z + q1.w * k1.w
                      + q2.x * k2.x + q2.y * k2.y + q2.z * k2.z + q2.w * k2.w
                      + q3.x * k3.x + q3.y * k3.y + q3.z * k3.z + q3.w * k3.w;
            float w = __expf(dot * scale);
            sum += w;
            float4 v0 = *(const float4*)&s_v[s][h * DK];
            float4 v1 = *(const float4*)&s_v[s][h * DK + 4];
            float4 v2 = *(const float4*)&s_v[s][h * DK + 8];
            float4 v3 = *(const float4*)&s_v[s][h * DK + 12];
            val[0] += w * v0.x;  val[1] += w * v0.y;  val[2] += w * v0.z;  val[3] += w * v0.w;
            val[4] += w * v1.x;  val[5] += w * v1.y;  val[6] += w * v1.z;  val[7] += w * v1.w;
            val[8] += w * v2.x;  val[9] += w * v2.y;  val[10] += w * v2.z; val[11] += w * v2.w;
            val[12] += w * v3.x; val[13] += w * v3.y; val[14] += w * v3.z; val[15] += w * v3.w;
        }
        float inv = 1.f / sum;
#pragma unroll
        for (int d = 0; d < DK; ++d) s_val[t][h * DK + d] = val[d] * inv;
    } else {
        for (int idx = tid - 192; idx < TT * DD; idx += 192)
            s_gcn[idx >> 6][idx & 63] = gcn_out[base + idx];
    }
    __syncthreads();

    int tq = tid >> 4;          // 0..23
    int dd0 = (tid & 15) * 4;

    {   // value = lrelu(val @ out_w + out_b)
        float4 a = *(const float4*)&out_b[dd0];
        for (int j0 = 0; j0 < E2; j0 += 4) {
            const float4 x = *(const float4*)&s_val[tq][j0];
            const float4 w0 = *(const float4*)&out_w[(j0 + 0) * DD + dd0];
            const float4 w1 = *(const float4*)&out_w[(j0 + 1) * DD + dd0];
            const float4 w2 = *(const float4*)&out_w[(j0 + 2) * DD + dd0];
            const float4 w3 = *(const float4*)&out_w[(j0 + 3) * DD + dd0];
            a.x += x.x * w0.x + x.y * w1.x + x.z * w2.x + x.w * w3.x;
            a.y += x.x * w0.y + x.y * w1.y + x.z * w2.y + x.w * w3.y;
            a.z += x.x * w0.z + x.y * w1.z + x.z * w2.z + x.w * w3.z;
            a.w += x.x * w0.w + x.y * w1.w + x.z * w2.w + x.w * w3.w;
        }
        a.x = (a.x >= 0.f) ? a.x : NEG * a.x;
        a.y = (a.y >= 0.f) ? a.y : NEG * a.y;
        a.z = (a.z >= 0.f) ? a.z : NEG * a.z;
        a.w = (a.w >= 0.f) ? a.w : NEG * a.w;
        *(float4*)&s_value[tq][dd0] = a;
    }
    __syncthreads();

    {   // gate + residual
        float4 zz = *(const float4*)&gate_b[dd0];
        for (int j0 = 0; j0 < DD; j0 += 4) {
            const float4 x = *(const float4*)&s_gcn[tq][j0];
            const float4 w0 = *(const float4*)&gate_w[(j0 + 0) * DD + dd0];
            const float4 w1 = *(const float4*)&gate_w[(j0 + 1) * DD + dd0];
            const float4 w2 = *(const float4*)&gate_w[(j0 + 2) * DD + dd0];
            const float4 w3 = *(const float4*)&gate_w[(j0 + 3) * DD + dd0];
            zz.x += x.x * w0.x + x.y * w1.x + x.z * w2.x + x.w * w3.x;
            zz.y += x.x * w0.y + x.y * w1.y + x.z * w2.y + x.w * w3.y;
            zz.z += x.x * w0.z + x.y * w1.z + x.z * w2.z + x.w * w3.z;
            zz.w += x.x * w0.w + x.y * w1.w + x.z * w2.w + x.w * w3.w;
        }
        for (int j0 = 0; j0 < DD; j0 += 4) {
            const float4 x = *(const float4*)&s_value[tq][j0];
            const float4 w0 = *(const float4*)&gate_w[(DD + j0 + 0) * DD + dd0];
            const float4 w1 = *(const float4*)&gate_w[(DD + j0 + 1) * DD + dd0];
            const float4 w2 = *(const float4*)&gate_w[(DD + j0 + 2) * DD + dd0];
            const float4 w3 = *(const float4*)&gate_w[(DD + j0 + 3) * DD + dd0];
            zz.x += x.x * w0.x + x.y * w1.x + x.z * w2.x + x.w * w3.x;
            zz.y += x.x * w0.y + x.y * w1.y + x.z * w2.y + x.w * w3.y;
            zz.z += x.x * w0.z + x.y * w1.z + x.z * w2.z + x.w * w3.z;
            zz.w += x.x * w0.w + x.y * w1.w + x.z * w2.w + x.w * w3.w;
        }
        size_t o = base + tq * DD + dd0;
        const float4 hv = *(const float4*)&hidden[o];
        const float4 gv = *(const float4*)&s_gcn[tq][dd0];
        const float4 vv = *(const float4*)&s_value[tq][dd0];
        float4 oo;
        float z;
        z = 1.f / (1.f + __expf(-zz.x)); oo.x = z * gv.x + (1.f - z) * vv.x + hv.x;
        z = 1.f / (1.f + __expf(-zz.y)); oo.y = z * gv.y + (1.f - z) * vv.y + hv.y;
        z = 1.f / (1.f + __expf(-zz.z)); oo.z = z * gv.z + (1.f - z) * vv.z + hv.z;
        z = 1.f / (1.f + __expf(-zz.w)); oo.w = z * gv.w + (1.f - z) * vv.w + hv.w;
        *(float4*)&out[o] = oo;
    }
}

extern "C" void kernel_launch(void* const* d_in, const int* in_sizes, int n_in,
                              void* d_out, int out_size, void* d_ws, size_t ws_size,
                              hipStream_t stream) {
    const float* hidden   = (const float*)d_in[0];
    const float* tXin     = (const float*)d_in[1];
    const float* matrix   = (const float*)d_in[2];
    const float* gcn_w    = (const float*)d_in[3];
    const float* gcn_b    = (const float*)d_in[4];
    const float* node_emb = (const float*)d_in[5];
    const float* tproj_w  = (const float*)d_in[6];
    const float* tproj_b  = (const float*)d_in[7];
    const float* WK_      = (const float*)d_in[8];   // dict order: WK, WQ, WV
    const float* WQ_      = (const float*)d_in[9];
    const float* WV_      = (const float*)d_in[10];
    const float* out_w    = (const float*)d_in[11];
    const float* out_b    = (const float*)d_in[12];
    const float* gate_w   = (const float*)d_in[13];
    const float* gate_b   = (const float*)d_in[14];
    float* out = (float*)d_out;

    char* ws = (char*)d_ws;
    float* tfeat   = (float*)ws;                         // 512 B
    float* gcn_out = (float*)(ws + 512);                 // 15,974,400 B
    size_t off_wp  = 512 + (size_t)BB * NN * TT * DD * 4;  // 15,974,912 (256-aligned)

    const size_t per_wp  = 3 * (size_t)E2 * E2 * 2;      // 98304 B per node (bf16)
    const size_t per_qkv = 3 * (size_t)TT * E2 * 2;      // 18432 B per node (bf16)
    long long avail = (long long)ws_size - (long long)off_wp;
    long long Ull = avail / (long long)(per_wp + per_qkv);
    int U = (Ull < 1) ? 1 : ((Ull > NNODE) ? NNODE : (int)Ull);

    unsigned short* wp_buf = (unsigned short*)(ws + off_wp);
    unsigned* qkv_buf = (unsigned*)(ws + off_wp + (size_t)U * per_wp);

    k_tfeat<<<BB, DD, 0, stream>>>(tXin, tproj_w, tproj_b, tfeat);
    k_gcn<<<dim3(BB * TT, (NN + TN - 1) / TN), 256, 0, stream>>>(matrix, hidden, gcn_w, gcn_b, gcn_out);

    for (int u0 = 0; u0 < NNODE; u0 += U) {
        int Uc = (NNODE - u0 < U) ? (NNODE - u0) : U;
        k_wp<<<dim3((Uc + 7) / 8, 48), 256, 0, stream>>>(node_emb, tfeat, WQ_, WK_, WV_,
                                                         wp_buf, u0, Uc);
        k_proj<<<Uc, 256, 0, stream>>>(hidden, tXin, wp_buf, qkv_buf, u0, Uc);
        k_attn2<<<Uc, 384, 0, stream>>>(qkv_buf, hidden, out_w, out_b, gate_w, gate_b,
                                        gcn_out, out, u0, Uc);
    }
}

// Round 6
// 547.294 us; speedup vs baseline: 6.4579x; 1.1387x over previous
//
#include <hip/hip_runtime.h>
#include <math.h>

#define BB 8
#define NN 325
#define TT 24
#define DD 64
#define HH 8
#define MM 16
#define E2 128
#define DK 16
#define NEG 0.1f
#define NNODE (BB * NN)          // 2600

__device__ __forceinline__ unsigned short f2bf(float f) {
    union { float f; unsigned u; } v; v.f = f;
    unsigned r = v.u + 0x7fffu + ((v.u >> 16) & 1u);   // RNE
    return (unsigned short)(r >> 16);
}
__device__ __forceinline__ unsigned packbf(float a, float b) {
    return (unsigned)f2bf(a) | ((unsigned)f2bf(b) << 16);
}
__device__ __forceinline__ float bflo(unsigned u) { return __uint_as_float(u << 16); }
__device__ __forceinline__ float bfhi(unsigned u) { return __uint_as_float(u & 0xffff0000u); }

// ---------------- K1: tfeat[b][m] = tanh(mean_t(tXin[b,0,t,:]) @ tproj_w + tproj_b)
__global__ void k_tfeat(const float* __restrict__ tXin, const float* __restrict__ tproj_w,
                        const float* __restrict__ tproj_b, float* __restrict__ tfeat) {
    int b = blockIdx.x;
    int d = threadIdx.x;  // 64 threads
    __shared__ float mv[DD];
    float a = 0.f;
    for (int t = 0; t < TT; ++t)
        a += tXin[((size_t)(b * NN + 0) * TT + t) * DD + d];
    mv[d] = a * (1.f / (float)TT);
    __syncthreads();
    if (d < MM) {
        float acc = tproj_b[d];
        for (int j = 0; j < DD; ++j) acc += mv[j] * tproj_w[j * MM + d];
        tfeat[b * MM + d] = tanhf(acc);
    }
}

// ---------------- K2: support = einsum('btnm,bmtd->bntd'); gcn_out = relu(support@gcn_w + b)
#define TN 64
__global__ __launch_bounds__(256) void k_gcn(const float* __restrict__ matrix,
                                             const float* __restrict__ hidden,
                                             const float* __restrict__ gcn_w,
                                             const float* __restrict__ gcn_b,
                                             float* __restrict__ gcn_out) {
    int bt = blockIdx.x;
    int tile = blockIdx.y;
    int b = bt / TT, t = bt % TT;
    int n0 = tile * TN;

    __shared__ float s_mat[TN][68];
    __shared__ float s_H[64][DD];
    __shared__ float s_gw[DD][DD];

    int tid = threadIdx.x;
    for (int idx = tid; idx < DD * DD; idx += 256)
        s_gw[idx / DD][idx % DD] = gcn_w[idx];

    int r  = tid >> 3;
    int d0 = (tid & 7) << 3;
    float acc0[8], acc1[8];
#pragma unroll
    for (int i = 0; i < 8; ++i) { acc0[i] = 0.f; acc1[i] = 0.f; }

    for (int m0 = 0; m0 < NN; m0 += 64) {
        __syncthreads();
        for (int idx = tid; idx < TN * 64; idx += 256) {
            int rr = idx >> 6, cc = idx & 63;
            int n = n0 + rr, m = m0 + cc;
            s_mat[rr][cc] = (n < NN && m < NN) ? matrix[((size_t)(b * TT + t) * NN + n) * NN + m] : 0.f;
        }
        for (int idx = tid; idx < 64 * DD; idx += 256) {
            int mm = idx >> 6, d = idx & 63;
            int m = m0 + mm;
            s_H[mm][d] = (m < NN) ? hidden[((size_t)(b * NN + m) * TT + t) * DD + d] : 0.f;
        }
        __syncthreads();
        int mmax = (NN - m0 < 64) ? (NN - m0) : 64;
        for (int mm = 0; mm < mmax; ++mm) {
            float w0 = s_mat[r][mm];
            float w1 = s_mat[r + 32][mm];
            float4 h0 = *(const float4*)&s_H[mm][d0];
            float4 h1 = *(const float4*)&s_H[mm][d0 + 4];
            acc0[0] += w0 * h0.x; acc0[1] += w0 * h0.y; acc0[2] += w0 * h0.z; acc0[3] += w0 * h0.w;
            acc0[4] += w0 * h1.x; acc0[5] += w0 * h1.y; acc0[6] += w0 * h1.z; acc0[7] += w0 * h1.w;
            acc1[0] += w1 * h0.x; acc1[1] += w1 * h0.y; acc1[2] += w1 * h0.z; acc1[3] += w1 * h0.w;
            acc1[4] += w1 * h1.x; acc1[5] += w1 * h1.y; acc1[6] += w1 * h1.z; acc1[7] += w1 * h1.w;
        }
    }

    __syncthreads();
    *(float4*)&s_H[r][d0]          = make_float4(acc0[0], acc0[1], acc0[2], acc0[3]);
    *(float4*)&s_H[r][d0 + 4]      = make_float4(acc0[4], acc0[5], acc0[6], acc0[7]);
    *(float4*)&s_H[r + 32][d0]     = make_float4(acc1[0], acc1[1], acc1[2], acc1[3]);
    *(float4*)&s_H[r + 32][d0 + 4] = make_float4(acc1[4], acc1[5], acc1[6], acc1[7]);
    __syncthreads();

    float g0[8], g1[8];
#pragma unroll
    for (int i = 0; i < 8; ++i) { g0[i] = gcn_b[d0 + i]; g1[i] = g0[i]; }
    for (int d = 0; d < DD; ++d) {
        float s0 = s_H[r][d], s1 = s_H[r + 32][d];
        float4 w0 = *(const float4*)&s_gw[d][d0];
        float4 w1 = *(const float4*)&s_gw[d][d0 + 4];
        g0[0] += s0 * w0.x; g0[1] += s0 * w0.y; g0[2] += s0 * w0.z; g0[3] += s0 * w0.w;
        g0[4] += s0 * w1.x; g0[5] += s0 * w1.y; g0[6] += s0 * w1.z; g0[7] += s0 * w1.w;
        g1[0] += s1 * w0.x; g1[1] += s1 * w0.y; g1[2] += s1 * w0.z; g1[3] += s1 * w0.w;
        g1[4] += s1 * w1.x; g1[5] += s1 * w1.y; g1[6] += s1 * w1.z; g1[7] += s1 * w1.w;
    }
#pragma unroll
    for (int i = 0; i < 8; ++i) {
        g0[i] = g0[i] > 0.f ? g0[i] : 0.f;
        g1[i] = g1[i] > 0.f ? g1[i] : 0.f;
    }
    if (n0 + r < NN) {
        size_t base = ((size_t)(b * NN + (n0 + r)) * TT + t) * DD;
        *(float4*)&gcn_out[base + d0]     = make_float4(g0[0], g0[1], g0[2], g0[3]);
        *(float4*)&gcn_out[base + d0 + 4] = make_float4(g0[4], g0[5], g0[6], g0[7]);
    }
    if (n0 + r + 32 < NN) {
        size_t base = ((size_t)(b * NN + (n0 + r + 32)) * TT + t) * DD;
        *(float4*)&gcn_out[base + d0]     = make_float4(g1[0], g1[1], g1[2], g1[3]);
        *(float4*)&gcn_out[base + d0 + 4] = make_float4(g1[4], g1[5], g1[6], g1[7]);
    }
}

// ---------------- K3a: Wp[u][p][i][k] (bf16) = sum_m e[u][m] * W_p[m][i][k]
// grid (ceil(Uc/16), 48); block 256. 16 nodes share each W read (W L2-resident).
__global__ __launch_bounds__(256) void k_wp(
    const float* __restrict__ node_emb, const float* __restrict__ tfeat,
    const float* __restrict__ WQ, const float* __restrict__ WK, const float* __restrict__ WV,
    unsigned short* __restrict__ wp, int u0, int Uc) {
    int un0 = blockIdx.x * 16;
    int chunk = blockIdx.y;                 // 0..47
    int p = chunk >> 4;                     // 0=Q 1=K 2=V
    int off = (chunk & 15) << 10;           // 1024-col chunk within 16384
    int tid = threadIdx.x;
    const float* __restrict__ W = (p == 0) ? WQ : ((p == 1) ? WK : WV);

    __shared__ float s_e[16][MM];
    {
        int nn = tid >> 4, m = tid & 15;    // 256 = 16*16 exactly
        int us = un0 + nn;
        float e = 0.f;
        if (us < Uc) {
            int u = u0 + us;
            int b = u / NN, n = u % NN;
            e = node_emb[n * MM + m] * tfeat[b * MM + m];
        }
        s_e[nn][m] = e;
    }
    __syncthreads();

    int j = off + tid * 4;
    float4 acc[16];
#pragma unroll
    for (int nn = 0; nn < 16; ++nn) acc[nn] = make_float4(0.f, 0.f, 0.f, 0.f);
#pragma unroll
    for (int m = 0; m < MM; ++m) {
        float4 w = *(const float4*)&W[(size_t)m * 16384 + j];
#pragma unroll
        for (int nn = 0; nn < 16; ++nn) {
            float e = s_e[nn][m];
            acc[nn].x += e * w.x; acc[nn].y += e * w.y;
            acc[nn].z += e * w.z; acc[nn].w += e * w.w;
        }
    }
#pragma unroll
    for (int nn = 0; nn < 16; ++nn) {
        int us = un0 + nn;
        if (us < Uc) {
            uint2 pk;
            pk.x = packbf(acc[nn].x, acc[nn].y);
            pk.y = packbf(acc[nn].z, acc[nn].w);
            *(uint2*)&wp[(size_t)us * 49152 + (size_t)p * 16384 + j] = pk;
        }
    }
}

// ---------------- K3b (fused): per node: proj (stream Wp) -> attention -> out-proj -> gate -> residual
// 256 threads; LDS ~49.9 KB -> 3 blocks/CU.
// arena u32[9216] (36864 B):
//   phase A: s_x f32[24][128] @0 (12288 B) | s_w u32[3][32][64] @3072 (24576 B)
//   phase B+: qkv u32[3][24][66] @0 (19008 B) | sc u32[8][24][13] @4752 (9984 B) | val u32[24][66] @7248 (6336 B)
#define QKS 66
#define QKP (TT * QKS)          // 1584 u32 per proj plane
#define SC_OFF 4752
#define VAL_OFF 7248
__global__ __launch_bounds__(256) void k_fuse(
    const float* __restrict__ hidden, const float* __restrict__ tXin,
    const unsigned short* __restrict__ wp,
    const float* __restrict__ out_w, const float* __restrict__ out_b,
    const float* __restrict__ gate_w, const float* __restrict__ gate_b,
    const float* __restrict__ gcn_out, float* __restrict__ out,
    int u0) {
    int us = blockIdx.x;
    int u = u0 + us;
    int tid = threadIdx.x;

    __shared__ __align__(16) unsigned arena[9216];
    __shared__ float s_gcn[TT][68];
    __shared__ float s_value[TT][68];

    float* s_x = (float*)arena;                 // [24][128]
    unsigned* s_w = arena + 3072;               // [3][32][64]

    size_t base = (size_t)u * TT * DD;

    // ---- phase A: load x (hidden|tXin) + gcn staging
    for (int idx = tid; idx < TT * 32; idx += 256) {
        int t = idx >> 5, q4 = idx & 31;
        float4 v = (q4 < 16) ? *(const float4*)&hidden[base + t * DD + q4 * 4]
                             : *(const float4*)&tXin[base + t * DD + (q4 - 16) * 4];
        *(float4*)&s_x[t * E2 + q4 * 4] = v;
    }
    for (int idx = tid; idx < TT * DD; idx += 256)
        s_gcn[idx >> 6][idx & 63] = gcn_out[base + idx];

    // ---- proj: stream Wp through LDS, acc[3][6][2] per thread
    int kg = tid & 63, tg = tid >> 6;
    int t0 = tg * 6;
    float acc[3][6][2];
#pragma unroll
    for (int p = 0; p < 3; ++p)
#pragma unroll
        for (int tt = 0; tt < 6; ++tt) { acc[p][tt][0] = 0.f; acc[p][tt][1] = 0.f; }

    const size_t wpb = (size_t)us * 49152;      // u16 units
    for (int ic = 0; ic < 4; ++ic) {
        __syncthreads();
#pragma unroll
        for (int p = 0; p < 3; ++p) {
            const uint4* src = (const uint4*)(wp + wpb + p * 16384 + ic * 4096);
            uint4* dst = (uint4*)&s_w[p * 2048];
            dst[tid] = src[tid];
            dst[tid + 256] = src[tid + 256];
        }
        __syncthreads();
#pragma unroll 4
        for (int i = 0; i < 32; ++i) {
            float xv[6];
#pragma unroll
            for (int tt = 0; tt < 6; ++tt) xv[tt] = s_x[(t0 + tt) * E2 + ic * 32 + i];
#pragma unroll
            for (int p = 0; p < 3; ++p) {
                unsigned w = s_w[p * 2048 + i * 64 + kg];
                float lo = bflo(w), hi = bfhi(w);
#pragma unroll
                for (int tt = 0; tt < 6; ++tt) {
                    acc[p][tt][0] += xv[tt] * lo;
                    acc[p][tt][1] += xv[tt] * hi;
                }
            }
        }
    }
    __syncthreads();   // s_x/s_w dead

    // ---- phase B: lrelu + write packed qkv
    unsigned* s_qkv = arena;
#pragma unroll
    for (int p = 0; p < 3; ++p)
#pragma unroll
        for (int tt = 0; tt < 6; ++tt) {
            float a0 = acc[p][tt][0]; a0 = (a0 >= 0.f) ? a0 : NEG * a0;
            float a1 = acc[p][tt][1]; a1 = (a1 >= 0.f) ? a1 : NEG * a1;
            s_qkv[p * QKP + (t0 + tt) * QKS + kg] = packbf(a0, a1);
        }
    __syncthreads();

    // ---- phase C1: scores w[h][t][s] = exp(scale * q.k) for s<=t, 0 otherwise (packed pairs)
    unsigned* s_sc = arena + SC_OFF;
    if (tid < HH * TT) {
        int h = tid / TT, t = tid % TT;
        const float scale = 0.25f;
        float qf[16];
#pragma unroll
        for (int j = 0; j < 8; ++j) {
            unsigned uq = s_qkv[0 * QKP + t * QKS + 8 * h + j];
            qf[2 * j] = bflo(uq); qf[2 * j + 1] = bfhi(uq);
        }
#pragma unroll
        for (int s2 = 0; s2 < 12; ++s2) {
            int s0 = 2 * s2;
            float d0 = 0.f, d1 = 0.f;
#pragma unroll
            for (int j = 0; j < 8; ++j) {
                unsigned ka = s_qkv[1 * QKP + s0 * QKS + 8 * h + j];
                unsigned kb = s_qkv[1 * QKP + (s0 + 1) * QKS + 8 * h + j];
                d0 += qf[2 * j] * bflo(ka) + qf[2 * j + 1] * bfhi(ka);
                d1 += qf[2 * j] * bflo(kb) + qf[2 * j + 1] * bfhi(kb);
            }
            float w0 = (s0 <= t) ? __expf(d0 * scale) : 0.f;
            float w1 = (s0 + 1 <= t) ? __expf(d1 * scale) : 0.f;
            s_sc[(h * TT + t) * 13 + s2] = packbf(w0, w1);
        }
    }
    __syncthreads();

    // ---- phase C2: normalize + PV -> packed val[24][66]
    unsigned* s_val = arena + VAL_OFF;
#pragma unroll
    for (int it = 0; it < 3; ++it) {
        int item = tid + it * 256;             // < 768
        int h = item / 96;
        int r = item % 96;
        int t = r >> 2, d4 = r & 3;
        int kg0 = 8 * h + 2 * d4;
        float sum = 0.f, v0 = 0.f, v1 = 0.f, v2 = 0.f, v3 = 0.f;
#pragma unroll
        for (int s2 = 0; s2 < 12; ++s2) {
            unsigned uw = s_sc[(h * TT + t) * 13 + s2];
            float w0 = bflo(uw), w1 = bfhi(uw);
            sum += w0 + w1;
            unsigned ua = s_qkv[2 * QKP + (2 * s2) * QKS + kg0];
            unsigned ub = s_qkv[2 * QKP + (2 * s2) * QKS + kg0 + 1];
            v0 += w0 * bflo(ua); v1 += w0 * bfhi(ua);
            v2 += w0 * bflo(ub); v3 += w0 * bfhi(ub);
            unsigned uc = s_qkv[2 * QKP + (2 * s2 + 1) * QKS + kg0];
            unsigned ud = s_qkv[2 * QKP + (2 * s2 + 1) * QKS + kg0 + 1];
            v0 += w1 * bflo(uc); v1 += w1 * bfhi(uc);
            v2 += w1 * bflo(ud); v3 += w1 * bfhi(ud);
        }
        float inv = 1.f / sum;
        s_val[t * QKS + kg0]     = packbf(v0 * inv, v1 * inv);
        s_val[t * QKS + kg0 + 1] = packbf(v2 * inv, v3 * inv);
    }
    __syncthreads();

    // ---- phase D: value = lrelu(val @ out_w + out_b)
    for (int o = tid; o < TT * 16; o += 256) {
        int tq = o >> 4;
        int dd0 = (o & 15) * 4;
        float4 a = *(const float4*)&out_b[dd0];
        for (int j0 = 0; j0 < E2; j0 += 4) {
            unsigned xa = s_val[tq * QKS + j0 / 2];
            unsigned xb = s_val[tq * QKS + j0 / 2 + 1];
            float x0 = bflo(xa), x1 = bfhi(xa), x2 = bflo(xb), x3 = bfhi(xb);
            const float4 w0 = *(const float4*)&out_w[(j0 + 0) * DD + dd0];
            const float4 w1 = *(const float4*)&out_w[(j0 + 1) * DD + dd0];
            const float4 w2 = *(const float4*)&out_w[(j0 + 2) * DD + dd0];
            const float4 w3 = *(const float4*)&out_w[(j0 + 3) * DD + dd0];
            a.x += x0 * w0.x + x1 * w1.x + x2 * w2.x + x3 * w3.x;
            a.y += x0 * w0.y + x1 * w1.y + x2 * w2.y + x3 * w3.y;
            a.z += x0 * w0.z + x1 * w1.z + x2 * w2.z + x3 * w3.z;
            a.w += x0 * w0.w + x1 * w1.w + x2 * w2.w + x3 * w3.w;
        }
        a.x = (a.x >= 0.f) ? a.x : NEG * a.x;
        a.y = (a.y >= 0.f) ? a.y : NEG * a.y;
        a.z = (a.z >= 0.f) ? a.z : NEG * a.z;
        a.w = (a.w >= 0.f) ? a.w : NEG * a.w;
        *(float4*)&s_value[tq][dd0] = a;
    }
    __syncthreads();

    // ---- phase E: gate + residual
    for (int o = tid; o < TT * 16; o += 256) {
        int tq = o >> 4;
        int dd0 = (o & 15) * 4;
        float4 zz = *(const float4*)&gate_b[dd0];
        for (int j0 = 0; j0 < DD; j0 += 4) {
            const float4 x = *(const float4*)&s_gcn[tq][j0];
            const float4 w0 = *(const float4*)&gate_w[(j0 + 0) * DD + dd0];
            const float4 w1 = *(const float4*)&gate_w[(j0 + 1) * DD + dd0];
            const float4 w2 = *(const float4*)&gate_w[(j0 + 2) * DD + dd0];
            const float4 w3 = *(const float4*)&gate_w[(j0 + 3) * DD + dd0];
            zz.x += x.x * w0.x + x.y * w1.x + x.z * w2.x + x.w * w3.x;
            zz.y += x.x * w0.y + x.y * w1.y + x.z * w2.y + x.w * w3.y;
            zz.z += x.x * w0.z + x.y * w1.z + x.z * w2.z + x.w * w3.z;
            zz.w += x.x * w0.w + x.y * w1.w + x.z * w2.w + x.w * w3.w;
        }
        for (int j0 = 0; j0 < DD; j0 += 4) {
            const float4 x = *(const float4*)&s_value[tq][j0];
            const float4 w0 = *(const float4*)&gate_w[(DD + j0 + 0) * DD + dd0];
            const float4 w1 = *(const float4*)&gate_w[(DD + j0 + 1) * DD + dd0];
            const float4 w2 = *(const float4*)&gate_w[(DD + j0 + 2) * DD + dd0];
            const float4 w3 = *(const float4*)&gate_w[(DD + j0 + 3) * DD + dd0];
            zz.x += x.x * w0.x + x.y * w1.x + x.z * w2.x + x.w * w3.x;
            zz.y += x.x * w0.y + x.y * w1.y + x.z * w2.y + x.w * w3.y;
            zz.z += x.x * w0.z + x.y * w1.z + x.z * w2.z + x.w * w3.z;
            zz.w += x.x * w0.w + x.y * w1.w + x.z * w2.w + x.w * w3.w;
        }
        size_t ob = base + tq * DD + dd0;
        const float4 hv = *(const float4*)&hidden[ob];
        const float4 gv = *(const float4*)&s_gcn[tq][dd0];
        const float4 vv = *(const float4*)&s_value[tq][dd0];
        float4 oo;
        float z;
        z = 1.f / (1.f + __expf(-zz.x)); oo.x = z * gv.x + (1.f - z) * vv.x + hv.x;
        z = 1.f / (1.f + __expf(-zz.y)); oo.y = z * gv.y + (1.f - z) * vv.y + hv.y;
        z = 1.f / (1.f + __expf(-zz.z)); oo.z = z * gv.z + (1.f - z) * vv.z + hv.z;
        z = 1.f / (1.f + __expf(-zz.w)); oo.w = z * gv.w + (1.f - z) * vv.w + hv.w;
        *(float4*)&out[ob] = oo;
    }
}

extern "C" void kernel_launch(void* const* d_in, const int* in_sizes, int n_in,
                              void* d_out, int out_size, void* d_ws, size_t ws_size,
                              hipStream_t stream) {
    const float* hidden   = (const float*)d_in[0];
    const float* tXin     = (const float*)d_in[1];
    const float* matrix   = (const float*)d_in[2];
    const float* gcn_w    = (const float*)d_in[3];
    const float* gcn_b    = (const float*)d_in[4];
    const float* node_emb = (const float*)d_in[5];
    const float* tproj_w  = (const float*)d_in[6];
    const float* tproj_b  = (const float*)d_in[7];
    const float* WK_      = (const float*)d_in[8];   // dict order: WK, WQ, WV
    const float* WQ_      = (const float*)d_in[9];
    const float* WV_      = (const float*)d_in[10];
    const float* out_w    = (const float*)d_in[11];
    const float* out_b    = (const float*)d_in[12];
    const float* gate_w   = (const float*)d_in[13];
    const float* gate_b   = (const float*)d_in[14];
    float* out = (float*)d_out;

    char* ws = (char*)d_ws;
    float* tfeat   = (float*)ws;                         // 512 B
    float* gcn_out = (float*)(ws + 512);                 // 15,974,400 B
    size_t off_wp  = 512 + (size_t)BB * NN * TT * DD * 4;

    const size_t per_wp = 3 * (size_t)E2 * E2 * 2;       // 98304 B per node (bf16)
    long long avail = (long long)ws_size - (long long)off_wp;
    long long Ull = avail / (long long)per_wp;
    int U = (Ull < 1) ? 1 : ((Ull > NNODE) ? NNODE : (int)Ull);

    unsigned short* wp_buf = (unsigned short*)(ws + off_wp);

    k_tfeat<<<BB, DD, 0, stream>>>(tXin, tproj_w, tproj_b, tfeat);
    k_gcn<<<dim3(BB * TT, (NN + TN - 1) / TN), 256, 0, stream>>>(matrix, hidden, gcn_w, gcn_b, gcn_out);

    for (int u0 = 0; u0 < NNODE; u0 += U) {
        int Uc = (NNODE - u0 < U) ? (NNODE - u0) : U;
        k_wp<<<dim3((Uc + 15) / 16, 48), 256, 0, stream>>>(node_emb, tfeat, WQ_, WK_, WV_,
                                                           wp_buf, u0, Uc);
        k_fuse<<<Uc, 256, 0, stream>>>(hidden, tXin, wp_buf, out_w, out_b,
                                       gate_w, gate_b, gcn_out, out, u0);
    }
}